// Round 6
// baseline (1505.250 us; speedup 1.0000x reference)
//
#include <hip/hip_runtime.h>

#define P_ 128
#define T_ 2048
#define D_ 128
#define H_ 64
#define G_ 192
#define OUT_ 24

typedef float v2f __attribute__((ext_vector_type(2)));

__device__ __forceinline__ float rcpf_(float x){ return __builtin_amdgcn_rcpf(x); }
__device__ __forceinline__ float sigmoidf_(float x){ return rcpf_(1.0f + __expf(-x)); }
// tanh(x) = 1 - 2/(e^{2x}+1): branch-free, saturates correctly at +/-inf.
__device__ __forceinline__ float tanhf_(float x){
  float e = __expf(2.0f*x);
  return 1.0f - 2.0f*rcpf_(e + 1.0f);
}

// ---------------- Phase 1: x_proj[p, tl, g] = sum_d z[p,t0+tl,d]*w_ih[p,g,d] + b_ih[p,g]
__global__ __launch_bounds__(256) void xproj_kernel(
    const float* __restrict__ z, const float* __restrict__ w_ih,
    const float* __restrict__ b_ih, float* __restrict__ xp,
    int t0, int tcLen)
{
  __shared__ float zl[64*132];
  const int p = blockIdx.y;
  const int tBase = blockIdx.x*64;
  const int tid = threadIdx.x;
  const float* zg = z + ((size_t)p*T_ + (size_t)(t0 + tBase))*D_;
  #pragma unroll
  for (int i=0;i<8;i++){
    int idx = tid + i*256;
    int r = idx >> 5, c = idx & 31;
    *(float4*)(zl + r*132 + c*4) = *(const float4*)(zg + (size_t)r*D_ + c*4);
  }
  __syncthreads();

  const int tg = tid & 15, ng = tid >> 4;
  const int n0 = ng*12, tr = tg*4;
  const float* wg = w_ih + (size_t)p*G_*D_;
  float acc[4][12];
  #pragma unroll
  for (int j=0;j<12;j++){
    float b = b_ih[p*G_ + n0 + j];
    #pragma unroll
    for (int i=0;i<4;i++) acc[i][j] = b;
  }
  #pragma unroll 4
  for (int k=0;k<D_;k+=4){
    float4 x4[4];
    #pragma unroll
    for (int i=0;i<4;i++) x4[i] = *(const float4*)(zl + (tr+i)*132 + k);
    #pragma unroll
    for (int j=0;j<12;j++){
      float4 w4 = *(const float4*)(wg + (size_t)(n0+j)*D_ + k);
      #pragma unroll
      for (int i=0;i<4;i++)
        acc[i][j] = fmaf(x4[i].x,w4.x, fmaf(x4[i].y,w4.y, fmaf(x4[i].z,w4.z, fmaf(x4[i].w,w4.w, acc[i][j]))));
    }
  }
  float* orow = xp + ((size_t)p*tcLen + tBase)*G_;
  #pragma unroll
  for (int i=0;i<4;i++){
    #pragma unroll
    for (int j3=0;j3<3;j3++){
      float4 v = make_float4(acc[i][j3*4+0],acc[i][j3*4+1],acc[i][j3*4+2],acc[i][j3*4+3]);
      *(float4*)(orow + (size_t)(tr+i)*G_ + n0 + j3*4) = v;
    }
  }
}

// ---------------- Phase 2: GRU recurrence. THREE WAVES per part, one gate each.
// Weights stay resident in VGPRs (64 regs/wave). Per step: private-LDS h
// broadcast -> 32 pk-FMAs -> gate nonlinearity -> RAW s_barrier that drains
// lgkmcnt ONLY (NOT __syncthreads: its vmcnt(0) drain would force the global
// x-prefetch loads and the hs store to COMPLETE inside the serial critical
// path every step, ~300-600cy). Exchange gx is double-buffered; hbc is
// wave-private; identical trip counts => barrier-per-step resyncs, no race.
__global__ __launch_bounds__(192, 1) void gru_kernel(
    const float* __restrict__ xp, const float* __restrict__ w_hh,
    const float* __restrict__ b_hh, float* __restrict__ hs,
    float* __restrict__ hstate, int t0, int tcLen)
{
  __shared__ __align__(16) float hbc[3][64];   // per-wave private h broadcast
  __shared__ float gx[2][3][64];               // gate exchange, double-buffered
  const int p = blockIdx.x;
  const int tid = threadIdx.x;
  const int w = tid >> 6;                      // wave id = gate id (0=r,1=z,2=n)
  const int l = tid & 63;

  // Weights for gate-row (64w + l): 32 v2f = 64 VGPRs. Fits in registers.
  v2f wg2[32];
  {
    const float* Wg = w_hh + ((size_t)p*G_ + 64*w + l)*H_;
    #pragma unroll
    for (int i=0;i<16;i++){
      float4 a = *(const float4*)(Wg + 4*i);
      wg2[2*i]   = v2f{a.x, a.y};
      wg2[2*i+1] = v2f{a.z, a.w};
    }
  }
  const float bg = b_hh[p*G_ + 64*w + l];

  float h = 0.0f;
  if (t0 != 0) h = hstate[p*H_ + l];
  hbc[w][l] = h;                               // seed own broadcast buffer

  const float* xrow = xp + (size_t)p*tcLen*G_;
  float xg_n = xrow[64*w + l];                 // own gate's x
  float xn_n = xrow[128 + l];                  // n-gate x (needed by all for tail)
  float* hsrow = hs + ((size_t)p*T_ + (size_t)t0)*H_;

  for (int tl=0; tl<tcLen; ++tl){
    float xg = xg_n, xn = xn_n;
    int tn = (tl+1 < tcLen) ? tl+1 : tl;       // wave-uniform select
    const float* xnrow = xrow + (size_t)tn*G_;
    xg_n = xnrow[64*w + l];
    xn_n = xnrow[128 + l];

    // h broadcast: 16 x ds_read_b128, all lanes same address (HW broadcast).
    float4 h4[16];
    #pragma unroll
    for (int j=0;j<16;j++) h4[j] = *(const float4*)(&hbc[w][4*j]);
    __builtin_amdgcn_sched_barrier(0);         // pin: reads issued before FMAs

    v2f acc = v2f{bg, 0.0f};
    #pragma unroll
    for (int j=0;j<16;j++){
      v2f h2a = v2f{h4[j].x, h4[j].y};
      v2f h2b = v2f{h4[j].z, h4[j].w};
      acc = __builtin_elementwise_fma(wg2[2*j],   h2a, acc);
      acc = __builtin_elementwise_fma(wg2[2*j+1], h2b, acc);
    }
    float dot = acc.x + acc.y;

    // gate-specific transform before exchange (wave-uniform branch)
    float gval = (w < 2) ? sigmoidf_(xg + dot) : dot;
    gx[tl&1][w][l] = gval;
    // Raw barrier: drain LDS ops only; global loads/stores stay in flight.
    asm volatile("s_waitcnt lgkmcnt(0)" ::: "memory");
    __builtin_amdgcn_s_barrier();
    asm volatile("" ::: "memory");
    float rv  = gx[tl&1][0][l];
    float uv  = gx[tl&1][1][l];
    float hnv = gx[tl&1][2][l];

    // redundant tail in all waves -> identical h everywhere (same ops, same data)
    float n = tanhf_(xn + rv*hnv);
    h = fmaf(uv, h - n, n);
    hbc[w][l] = h;                              // refresh own broadcast buffer
    if (w == 0) hsrow[(size_t)tl*H_ + l] = h;
  }
  if (w == 0) hstate[p*H_ + l] = h;
}

// ---------------- Phase 3: fused 4-layer MLP.
template<int K, int N, int NPT, bool RELU, bool TOGLOBAL>
__device__ __forceinline__ void layer_(
    const float* __restrict__ Xl, const float* __restrict__ Wg,
    const float* __restrict__ bg, float* Yl, float* outg, int tid)
{
  constexpr int NG = N / NPT;
  constexpr int XS = K + 4;
  constexpr int YS = N + 4;
  const int tg = tid & 15, ng = tid >> 4;
  if (ng < NG){
    const int tr = tg*4, n0 = ng*NPT;
    float acc[4][NPT];
    #pragma unroll
    for (int j=0;j<NPT;j++){
      float b = bg[n0+j];
      #pragma unroll
      for (int i=0;i<4;i++) acc[i][j] = b;
    }
    #pragma unroll 4
    for (int k=0;k<K;k+=4){
      float4 x4[4];
      #pragma unroll
      for (int i=0;i<4;i++) x4[i] = *(const float4*)(Xl + (tr+i)*XS + k);
      #pragma unroll
      for (int j=0;j<NPT;j++){
        float4 w4 = *(const float4*)(Wg + (size_t)(n0+j)*K + k);
        #pragma unroll
        for (int i=0;i<4;i++)
          acc[i][j] = fmaf(x4[i].x,w4.x, fmaf(x4[i].y,w4.y, fmaf(x4[i].z,w4.z, fmaf(x4[i].w,w4.w, acc[i][j]))));
      }
    }
    #pragma unroll
    for (int i=0;i<4;i++){
      #pragma unroll
      for (int j=0;j<NPT;j++){
        float v = acc[i][j];
        if (RELU) v = fmaxf(v, 0.0f);
        if (TOGLOBAL) outg[(size_t)(tr+i)*OUT_ + n0 + j] = v;
        else          Yl[(tr+i)*YS + n0 + j] = v;
      }
    }
  }
}

__global__ __launch_bounds__(256) void mlp_kernel(
    const float* __restrict__ hs,
    const float* __restrict__ w1, const float* __restrict__ b1,
    const float* __restrict__ w2, const float* __restrict__ b2,
    const float* __restrict__ w3, const float* __restrict__ b3,
    const float* __restrict__ w4, const float* __restrict__ b4,
    float* __restrict__ out)
{
  __shared__ float bufA[64*68];
  __shared__ float bufB[64*132];
  const int p = blockIdx.y;
  const int t0 = blockIdx.x*64;
  const int tid = threadIdx.x;

  const float* hg = hs + ((size_t)p*T_ + (size_t)t0)*H_;
  #pragma unroll
  for (int i=0;i<4;i++){
    int idx = tid + i*256;
    int r = idx >> 4, c = idx & 15;
    *(float4*)(bufA + r*68 + c*4) = *(const float4*)(hg + (size_t)r*H_ + c*4);
  }
  __syncthreads();
  layer_<64,128,8,true,false>(bufA, w1 + (size_t)p*128*64, b1 + p*128, bufB, nullptr, tid);
  __syncthreads();
  layer_<128,64,4,true,false>(bufB, w2 + (size_t)p*64*128, b2 + p*64, bufA, nullptr, tid);
  __syncthreads();
  layer_<64,32,2,true,false>(bufA, w3 + (size_t)p*32*64, b3 + p*32, bufB, nullptr, tid);
  __syncthreads();
  float* og = out + ((size_t)p*T_ + (size_t)t0)*OUT_;
  layer_<32,24,2,false,true>(bufB, w4 + (size_t)p*24*32, b4 + p*24, nullptr, og, tid);
}

extern "C" void kernel_launch(void* const* d_in, const int* in_sizes, int n_in,
                              void* d_out, int out_size, void* d_ws, size_t ws_size,
                              hipStream_t stream)
{
  const float* z    = (const float*)d_in[0];
  const float* w_ih = (const float*)d_in[1];
  const float* w_hh = (const float*)d_in[2];
  const float* b_ih = (const float*)d_in[3];
  const float* b_hh = (const float*)d_in[4];
  const float* w1 = (const float*)d_in[5];
  const float* b1 = (const float*)d_in[6];
  const float* w2 = (const float*)d_in[7];
  const float* b2 = (const float*)d_in[8];
  const float* w3 = (const float*)d_in[9];
  const float* b3 = (const float*)d_in[10];
  const float* w4 = (const float*)d_in[11];
  const float* b4 = (const float*)d_in[12];
  float* out = (float*)d_out;

  const size_t hsBytes = (size_t)P_*T_*H_*sizeof(float);
  const size_t stBytes = (size_t)P_*H_*sizeof(float);
  int tc = 64;
  for (int cand = T_; cand >= 64; cand >>= 1){
    size_t need = (size_t)P_*cand*G_*sizeof(float) + hsBytes + stBytes;
    if (need <= ws_size){ tc = cand; break; }
  }
  float* xp     = (float*)d_ws;
  float* hsbuf  = (float*)((char*)d_ws + (size_t)P_*tc*G_*sizeof(float));
  float* hstate = hsbuf + (size_t)P_*T_*H_;

  for (int t0 = 0; t0 < T_; t0 += tc){
    xproj_kernel<<<dim3(tc/64, P_), 256, 0, stream>>>(z, w_ih, b_ih, xp, t0, tc);
    gru_kernel<<<dim3(P_), 192, 0, stream>>>(xp, w_hh, b_hh, hsbuf, hstate, t0, tc);
  }
  mlp_kernel<<<dim3(T_/64, P_), 256, 0, stream>>>(hsbuf, w1,b1,w2,b2,w3,b3,w4,b4, out);
}

// Round 7
// 1337.910 us; speedup vs baseline: 1.1251x; 1.1251x over previous
//
#include <hip/hip_runtime.h>

#define P_ 128
#define T_ 2048
#define D_ 128
#define H_ 64
#define G_ 192
#define OUT_ 24

typedef float v2f __attribute__((ext_vector_type(2)));

__device__ __forceinline__ float rcpf_(float x){ return __builtin_amdgcn_rcpf(x); }
__device__ __forceinline__ float sigmoidf_(float x){ return rcpf_(1.0f + __expf(-x)); }
// tanh(x) = 1 - 2/(e^{2x}+1): branch-free, saturates correctly at +/-inf.
__device__ __forceinline__ float tanhf_(float x){
  float e = __expf(2.0f*x);
  return 1.0f - 2.0f*rcpf_(e + 1.0f);
}

// ---------------- Phase 1: x_proj[p, tl, g] = sum_d z[p,t0+tl,d]*w_ih[p,g,d] + b_ih[p,g]
__global__ __launch_bounds__(256) void xproj_kernel(
    const float* __restrict__ z, const float* __restrict__ w_ih,
    const float* __restrict__ b_ih, float* __restrict__ xp,
    int t0, int tcLen)
{
  __shared__ float zl[64*132];
  const int p = blockIdx.y;
  const int tBase = blockIdx.x*64;
  const int tid = threadIdx.x;
  const float* zg = z + ((size_t)p*T_ + (size_t)(t0 + tBase))*D_;
  #pragma unroll
  for (int i=0;i<8;i++){
    int idx = tid + i*256;
    int r = idx >> 5, c = idx & 31;
    *(float4*)(zl + r*132 + c*4) = *(const float4*)(zg + (size_t)r*D_ + c*4);
  }
  __syncthreads();

  const int tg = tid & 15, ng = tid >> 4;
  const int n0 = ng*12, tr = tg*4;
  const float* wg = w_ih + (size_t)p*G_*D_;
  float acc[4][12];
  #pragma unroll
  for (int j=0;j<12;j++){
    float b = b_ih[p*G_ + n0 + j];
    #pragma unroll
    for (int i=0;i<4;i++) acc[i][j] = b;
  }
  #pragma unroll 4
  for (int k=0;k<D_;k+=4){
    float4 x4[4];
    #pragma unroll
    for (int i=0;i<4;i++) x4[i] = *(const float4*)(zl + (tr+i)*132 + k);
    #pragma unroll
    for (int j=0;j<12;j++){
      float4 w4 = *(const float4*)(wg + (size_t)(n0+j)*D_ + k);
      #pragma unroll
      for (int i=0;i<4;i++)
        acc[i][j] = fmaf(x4[i].x,w4.x, fmaf(x4[i].y,w4.y, fmaf(x4[i].z,w4.z, fmaf(x4[i].w,w4.w, acc[i][j]))));
    }
  }
  float* orow = xp + ((size_t)p*tcLen + tBase)*G_;
  #pragma unroll
  for (int i=0;i<4;i++){
    #pragma unroll
    for (int j3=0;j3<3;j3++){
      float4 v = make_float4(acc[i][j3*4+0],acc[i][j3*4+1],acc[i][j3*4+2],acc[i][j3*4+3]);
      *(float4*)(orow + (size_t)(tr+i)*G_ + n0 + j3*4) = v;
    }
  }
}

// ---------------- Phase 2: GRU recurrence. SIX WAVES per part (gate x half-row).
// Per wave: 16 v2f weights = 32 VGPRs (unambiguously register-resident),
// 8 broadcast ds_read_b128 for its h-half, FMA chain depth 8 (2 accumulators).
// Waves write RAW partial dots to LDS (symmetric arrival at the barrier; no
// pre-barrier transcendentals), one lgkm-only barrier, then ALL waves
// redundantly: sum partials + bias, sigmoid r/u, tanh n, update h (bit-identical
// across waves) and refresh their PRIVATE h-broadcast copy -- no 2nd barrier.
// x loads are 2-steps-ahead ping-pong prefetched (~1000cy cover vs ~900cy L3).
__global__ __launch_bounds__(384, 1) void gru_kernel(
    const float* __restrict__ xp, const float* __restrict__ w_hh,
    const float* __restrict__ b_hh, float* __restrict__ hs,
    float* __restrict__ hstate, int t0, int tcLen)
{
  __shared__ __align__(16) float hbc[6][64];   // per-wave private h broadcast
  __shared__ float gxp[2][6][64];              // partial-dot exchange, dbuf
  const int p   = blockIdx.x;
  const int tid = threadIdx.x;
  const int w   = tid >> 6;                    // wave 0..5
  const int g   = w >> 1;                      // gate 0=r,1=z,2=n
  const int hf  = w & 1;                       // half of the dot
  const int l   = tid & 63;

  // Half gate-row: 16 v2f = 32 VGPRs.
  v2f wg2[16];
  {
    const float* Wg = w_hh + ((size_t)p*G_ + 64*g + l)*H_ + 32*hf;
    #pragma unroll
    for (int i=0;i<8;i++){
      float4 a = *(const float4*)(Wg + 4*i);
      wg2[2*i]   = v2f{a.x, a.y};
      wg2[2*i+1] = v2f{a.z, a.w};
    }
  }
  const float br = b_hh[p*G_ + l];
  const float bz = b_hh[p*G_ + 64 + l];
  const float bn = b_hh[p*G_ + 128 + l];

  float h = 0.0f;
  if (t0 != 0) h = hstate[p*H_ + l];
  hbc[w][l] = h;                               // seed own broadcast buffer

  const float* xrow = xp + (size_t)p*tcLen*G_;
  float* hsrow = hs + ((size_t)p*T_ + (size_t)t0)*H_;

  // 2-deep x prefetch (A=even steps, B=odd steps).
  float xrA = xrow[l], xzA = xrow[64+l], xnA = xrow[128+l];
  const float* x1 = xrow + G_;
  float xrB = x1[l], xzB = x1[64+l], xnB = x1[128+l];

  auto step = [&](float& xr, float& xz, float& xn, int tl){
    const int b = tl & 1;
    // h-half broadcast: 8 x ds_read_b128, all lanes same address.
    float4 h4[8];
    #pragma unroll
    for (int j=0;j<8;j++) h4[j] = *(const float4*)(&hbc[w][32*hf + 4*j]);
    __builtin_amdgcn_sched_barrier(0);         // pin reads (and earlier loads) here

    v2f a0 = v2f{0.0f, 0.0f}, a1 = v2f{0.0f, 0.0f};
    #pragma unroll
    for (int j=0;j<4;j++){
      v2f hA = v2f{h4[2*j].x,   h4[2*j].y};
      v2f hB = v2f{h4[2*j].z,   h4[2*j].w};
      v2f hC = v2f{h4[2*j+1].x, h4[2*j+1].y};
      v2f hD = v2f{h4[2*j+1].z, h4[2*j+1].w};
      a0 = __builtin_elementwise_fma(wg2[4*j],   hA, a0);
      a1 = __builtin_elementwise_fma(wg2[4*j+1], hB, a1);
      a0 = __builtin_elementwise_fma(wg2[4*j+2], hC, a0);
      a1 = __builtin_elementwise_fma(wg2[4*j+3], hD, a1);
    }
    v2f as = a0 + a1;
    gxp[b][w][l] = as.x + as.y;                // raw partial dot

    asm volatile("s_waitcnt lgkmcnt(0)" ::: "memory");
    __builtin_amdgcn_s_barrier();
    asm volatile("" ::: "memory");

    float dr = gxp[b][0][l] + gxp[b][1][l] + br;
    float du = gxp[b][2][l] + gxp[b][3][l] + bz;
    float dn = gxp[b][4][l] + gxp[b][5][l] + bn;
    float r = sigmoidf_(xr + dr);
    float u = sigmoidf_(xz + du);
    float n = tanhf_(fmaf(r, dn, xn));
    h = fmaf(u, h - n, n);
    hbc[w][l] = h;                             // refresh own broadcast buffer
    if (w == 0) hsrow[(size_t)tl*H_ + l] = h;

    // prefetch x for tl+2 into the just-consumed registers
    int tn = tl + 2; if (tn >= tcLen) tn = tcLen - 1;
    const float* xf = xrow + (size_t)tn*G_;
    xr = xf[l]; xz = xf[64+l]; xn = xf[128+l];
  };

  for (int tl = 0; tl < tcLen; tl += 2){       // tcLen is a multiple of 64
    step(xrA, xzA, xnA, tl);
    step(xrB, xzB, xnB, tl+1);
  }
  if (w == 0) hstate[p*H_ + l] = h;
}

// ---------------- Phase 3: fused 4-layer MLP.
template<int K, int N, int NPT, bool RELU, bool TOGLOBAL>
__device__ __forceinline__ void layer_(
    const float* __restrict__ Xl, const float* __restrict__ Wg,
    const float* __restrict__ bg, float* Yl, float* outg, int tid)
{
  constexpr int NG = N / NPT;
  constexpr int XS = K + 4;
  constexpr int YS = N + 4;
  const int tg = tid & 15, ng = tid >> 4;
  if (ng < NG){
    const int tr = tg*4, n0 = ng*NPT;
    float acc[4][NPT];
    #pragma unroll
    for (int j=0;j<NPT;j++){
      float b = bg[n0+j];
      #pragma unroll
      for (int i=0;i<4;i++) acc[i][j] = b;
    }
    #pragma unroll 4
    for (int k=0;k<K;k+=4){
      float4 x4[4];
      #pragma unroll
      for (int i=0;i<4;i++) x4[i] = *(const float4*)(Xl + (tr+i)*XS + k);
      #pragma unroll
      for (int j=0;j<NPT;j++){
        float4 w4 = *(const float4*)(Wg + (size_t)(n0+j)*K + k);
        #pragma unroll
        for (int i=0;i<4;i++)
          acc[i][j] = fmaf(x4[i].x,w4.x, fmaf(x4[i].y,w4.y, fmaf(x4[i].z,w4.z, fmaf(x4[i].w,w4.w, acc[i][j]))));
      }
    }
    #pragma unroll
    for (int i=0;i<4;i++){
      #pragma unroll
      for (int j=0;j<NPT;j++){
        float v = acc[i][j];
        if (RELU) v = fmaxf(v, 0.0f);
        if (TOGLOBAL) outg[(size_t)(tr+i)*OUT_ + n0 + j] = v;
        else          Yl[(tr+i)*YS + n0 + j] = v;
      }
    }
  }
}

__global__ __launch_bounds__(256) void mlp_kernel(
    const float* __restrict__ hs,
    const float* __restrict__ w1, const float* __restrict__ b1,
    const float* __restrict__ w2, const float* __restrict__ b2,
    const float* __restrict__ w3, const float* __restrict__ b3,
    const float* __restrict__ w4, const float* __restrict__ b4,
    float* __restrict__ out)
{
  __shared__ float bufA[64*68];
  __shared__ float bufB[64*132];
  const int p = blockIdx.y;
  const int t0 = blockIdx.x*64;
  const int tid = threadIdx.x;

  const float* hg = hs + ((size_t)p*T_ + (size_t)t0)*H_;
  #pragma unroll
  for (int i=0;i<4;i++){
    int idx = tid + i*256;
    int r = idx >> 4, c = idx & 15;
    *(float4*)(bufA + r*68 + c*4) = *(const float4*)(hg + (size_t)r*H_ + c*4);
  }
  __syncthreads();
  layer_<64,128,8,true,false>(bufA, w1 + (size_t)p*128*64, b1 + p*128, bufB, nullptr, tid);
  __syncthreads();
  layer_<128,64,4,true,false>(bufB, w2 + (size_t)p*64*128, b2 + p*64, bufA, nullptr, tid);
  __syncthreads();
  layer_<64,32,2,true,false>(bufA, w3 + (size_t)p*32*64, b3 + p*32, bufB, nullptr, tid);
  __syncthreads();
  float* og = out + ((size_t)p*T_ + (size_t)t0)*OUT_;
  layer_<32,24,2,false,true>(bufB, w4 + (size_t)p*24*32, b4 + p*24, nullptr, og, tid);
}

extern "C" void kernel_launch(void* const* d_in, const int* in_sizes, int n_in,
                              void* d_out, int out_size, void* d_ws, size_t ws_size,
                              hipStream_t stream)
{
  const float* z    = (const float*)d_in[0];
  const float* w_ih = (const float*)d_in[1];
  const float* w_hh = (const float*)d_in[2];
  const float* b_ih = (const float*)d_in[3];
  const float* b_hh = (const float*)d_in[4];
  const float* w1 = (const float*)d_in[5];
  const float* b1 = (const float*)d_in[6];
  const float* w2 = (const float*)d_in[7];
  const float* b2 = (const float*)d_in[8];
  const float* w3 = (const float*)d_in[9];
  const float* b3 = (const float*)d_in[10];
  const float* w4 = (const float*)d_in[11];
  const float* b4 = (const float*)d_in[12];
  float* out = (float*)d_out;

  const size_t hsBytes = (size_t)P_*T_*H_*sizeof(float);
  const size_t stBytes = (size_t)P_*H_*sizeof(float);
  int tc = 64;
  for (int cand = T_; cand >= 64; cand >>= 1){
    size_t need = (size_t)P_*cand*G_*sizeof(float) + hsBytes + stBytes;
    if (need <= ws_size){ tc = cand; break; }
  }
  float* xp     = (float*)d_ws;
  float* hsbuf  = (float*)((char*)d_ws + (size_t)P_*tc*G_*sizeof(float));
  float* hstate = hsbuf + (size_t)P_*T_*H_;

  for (int t0 = 0; t0 < T_; t0 += tc){
    xproj_kernel<<<dim3(tc/64, P_), 256, 0, stream>>>(z, w_ih, b_ih, xp, t0, tc);
    gru_kernel<<<dim3(P_), 384, 0, stream>>>(xp, w_hh, b_hh, hsbuf, hstate, t0, tc);
  }
  mlp_kernel<<<dim3(T_/64, P_), 256, 0, stream>>>(hsbuf, w1,b1,w2,b2,w3,b3,w4,b4, out);
}